// Round 10
// baseline (71.699 us; speedup 1.0000x reference)
//
#include <hip/hip_runtime.h>
#include <math.h>

#define DIM   2048
#define NEXP  64
#define TOPK  8
#define ROWS  32           // rows per block; 8 waves, split-K-8
#define NT    512
#define NBLK  512          // M / ROWS

typedef __attribute__((ext_vector_type(8)))  short bf16x8;
typedef __attribute__((ext_vector_type(16))) float f32x16;

#define MFMA(A, B, C) __builtin_amdgcn_mfma_f32_32x32x16_bf16(A, B, C, 0, 0, 0)
#define AS_BF(v) (*(const bf16x8*)&(v))

typedef __attribute__((address_space(3))) unsigned int       lds_uint;
typedef __attribute__((address_space(1))) const unsigned int glb_uint;

#define STR2(x) #x
#define STR(x) STR2(x)
// inline-asm 16B global load: cannot be sunk/reordered vs other volatile asm
#define GL16(dst, p, off) \
    asm volatile("global_load_dwordx4 %0, %1, off offset:" STR(off) \
                 : "=v"(dst) : "v"(p) : "memory")

__device__ inline unsigned int bfpack(float a, float b) {
    unsigned int ua = __float_as_uint(a), ub = __float_as_uint(b);
    unsigned int lo = (ua + 0x7FFFu + ((ua >> 16) & 1u)) >> 16;
    unsigned int hi = (ub + 0x7FFFu + ((ub >> 16) & 1u)) & 0xFFFF0000u;
    return hi | lo;
}
__device__ inline void split2pair(float a, float b, unsigned int& h, unsigned int& m) {
    h = bfpack(a, b);
    float ra = a - __uint_as_float(h << 16);
    float rb = b - __uint_as_float(h & 0xFFFF0000u);
    m = bfpack(ra, rb);
}

// w[e][k] f32 -> byte = wv*65536 + t*4096 + (eh*2+term)*1024 + (kh*32+le)*16
//   k = wv*256 + t*16 + kh*8 + j ; e = eh*32 + le
__global__ __launch_bounds__(256) void prep_kernel(const float* __restrict__ w,
                                                   unsigned int* __restrict__ wpack) {
    const int u = blockIdx.x * 256 + threadIdx.x;   // 0..16383
    const int e = u >> 8, k8 = u & 255;
    const float4 v0 = *(const float4*)(w + (size_t)e * DIM + k8 * 8);
    const float4 v1 = *(const float4*)(w + (size_t)e * DIM + k8 * 8 + 4);
    unsigned int h[4], m[4];
    split2pair(v0.x, v0.y, h[0], m[0]);
    split2pair(v0.z, v0.w, h[1], m[1]);
    split2pair(v1.x, v1.y, h[2], m[2]);
    split2pair(v1.z, v1.w, h[3], m[3]);
    const int wv = k8 >> 5, t = (k8 >> 1) & 15, kh = k8 & 1;
    const int eh = e >> 5, le = e & 31;
    char* base = (char*)wpack + (size_t)wv * 65536 + t * 4096
               + (eh * 2) * 1024 + (kh * 32 + le) * 16;
    *(uint4*)(base)        = (uint4){h[0], h[1], h[2], h[3]};   // term h
    *(uint4*)(base + 1024) = (uint4){m[0], m[1], m[2], m[3]};   // term m
}

__global__ __launch_bounds__(NT, 4) void router_kernel(
    const float* __restrict__ x,
    const unsigned int* __restrict__ wpack,
    const float* __restrict__ bias,
    float* __restrict__ out,     // [M*8] scores | [M*8] idx(f32) | [64] counts(f32)
    int* __restrict__ histws,    // [NBLK][64]
    int M)
{
    // GEMM phase: xtile[8 waves][2 slots][512 floats] = 32 KB (front of smem)
    // Epilogue:   lg[256][66] floats = 67584 B (aliases), hist after
    __shared__ __align__(16) char smem[67584 + 256];

    const int tid  = threadIdx.x;
    const int bid  = blockIdx.x;
    const int swz  = (bid & 7) * (NBLK / 8) + (bid >> 3);    // bijective XCD swizzle
    const int row0 = swz * ROWS;
    int* hist = (int*)(smem + 67584);
    if (tid < NEXP) hist[tid] = 0;

    const int wv   = tid >> 6;      // K-slice (split-K-8)
    const int lane = tid & 63;
    const int lr   = lane & 31;
    const int kh   = lane >> 5;

    // x DMA per-lane source (permuted so linear LDS = [d][q][r16] granules):
    //   lane -> (q = lane>>4, r16 = lane&15); DMA d covers rows d*16..+15
    const float* xg0 = x + (size_t)(row0 +  0 + (lane & 15)) * DIM + wv * 256 + (lane >> 4) * 4;
    const float* xg1 = x + (size_t)(row0 + 16 + (lane & 15)) * DIM + wv * 256 + (lane >> 4) * 4;
    // w fragment stream
    const char* wsl = (const char*)wpack + (size_t)wv * 65536 + lane * 16;
    // wave-private LDS base (floats)
    float* xtb = (float*)smem + wv * 1024;        // 2 slots x 512 floats
    // A-fragment read offset (floats): granule (lr, 2kh) then +256B
    const int rdo = (lr >> 4) * 256 + kh * 128 + (lr & 15) * 4;

    f32x16 acc0 = {}, acc1 = {};
    uint4 wH0_0, wM0_0, wH1_0, wM1_0;
    uint4 wH0_1, wM0_1, wH1_1, wM1_1;

#define ISSUE(s, tt) do { \
        __builtin_amdgcn_global_load_lds((glb_uint*)(const void*)(xg0 + (tt) * 16), \
                                         (lds_uint*)(void*)(xtb + (s) * 512), 16, 0, 0); \
        __builtin_amdgcn_global_load_lds((glb_uint*)(const void*)(xg1 + (tt) * 16), \
                                         (lds_uint*)(void*)(xtb + (s) * 512 + 256), 16, 0, 0); \
        asm volatile("" ::: "memory"); \
        { const char* p_ = wsl + (tt) * 4096; \
          GL16(wH0_##s, p_, 0);    GL16(wM0_##s, p_, 1024); \
          GL16(wH1_##s, p_, 2048); GL16(wM1_##s, p_, 3072); } \
    } while (0)

#define DOSPLIT(vlo, vhi, hv, mv) do { \
        unsigned int h_[4], m_[4]; \
        split2pair((vlo).x, (vlo).y, h_[0], m_[0]); \
        split2pair((vlo).z, (vlo).w, h_[1], m_[1]); \
        split2pair((vhi).x, (vhi).y, h_[2], m_[2]); \
        split2pair((vhi).z, (vhi).w, h_[3], m_[3]); \
        hv = (uint4){h_[0], h_[1], h_[2], h_[3]}; \
        mv = (uint4){m_[0], m_[1], m_[2], m_[3]}; \
    } while (0)

// one K16 tile: counted vmcnt, ds_read A-frag, split, 6 MFMA, then issue tile t+2
#define KITER(s, WAITLIT, ISS) do { \
        asm volatile("s_waitcnt vmcnt(" WAITLIT ")" ::: "memory"); \
        __builtin_amdgcn_sched_barrier(0); \
        float4 alo_ = *(const float4*)(xtb + (s) * 512 + rdo); \
        float4 ahi_ = *(const float4*)(xtb + (s) * 512 + rdo + 64); \
        uint4 ah_, am_; \
        DOSPLIT(alo_, ahi_, ah_, am_); \
        acc0 = MFMA(AS_BF(ah_), AS_BF(wH0_##s), acc0); \
        acc0 = MFMA(AS_BF(am_), AS_BF(wH0_##s), acc0); \
        acc0 = MFMA(AS_BF(ah_), AS_BF(wM0_##s), acc0); \
        acc1 = MFMA(AS_BF(ah_), AS_BF(wH1_##s), acc1); \
        acc1 = MFMA(AS_BF(am_), AS_BF(wH1_##s), acc1); \
        acc1 = MFMA(AS_BF(ah_), AS_BF(wM1_##s), acc1); \
        __builtin_amdgcn_sched_barrier(0); \
        ISS; \
    } while (0)

    // prologue: depth-2 ring
    ISSUE(0, 0); ISSUE(1, 1);
    KITER(0, "6", ISSUE(0, 2));
    KITER(1, "6", ISSUE(1, 3));
    KITER(0, "6", ISSUE(0, 4));
    KITER(1, "6", ISSUE(1, 5));
    KITER(0, "6", ISSUE(0, 6));
    KITER(1, "6", ISSUE(1, 7));
    KITER(0, "6", ISSUE(0, 8));
    KITER(1, "6", ISSUE(1, 9));
    KITER(0, "6", ISSUE(0, 10));
    KITER(1, "6", ISSUE(1, 11));
    KITER(0, "6", ISSUE(0, 12));
    KITER(1, "6", ISSUE(1, 13));
    KITER(0, "6", ISSUE(0, 14));
    KITER(1, "6", ISSUE(1, 15));
    KITER(0, "6", );
    KITER(1, "0", );
#undef KITER
#undef DOSPLIT
#undef ISSUE

    __syncthreads();

    // ---- split-K partials into lg[8*32][66] (aliases smem) ----
    float* lgf = (float*)smem;
    #pragma unroll
    for (int r = 0; r < 16; ++r) {
        const int rr = (r & 3) + 8 * (r >> 2) + 4 * kh;   // verified C-layout (m74/m101)
        lgf[(wv * 32 + rr) * 66 + lr]      = acc0[r];
        lgf[(wv * 32 + rr) * 66 + 32 + lr] = acc1[r];
    }
    __syncthreads();

    // ---- top-k + softmax + histogram (verified epilogue); wave wv: 4 rows ----
    float* out_scores = out;
    float* out_idx    = out + (size_t)M * TOPK;

    #pragma unroll
    for (int i = 0; i < 4; ++i) {
        const int row = wv * 4 + i;
        float vm = bias[lane];
        #pragma unroll
        for (int p = 0; p < 8; ++p) vm += lgf[(p * 32 + row) * 66 + lane];

        float vals[TOPK];
        int   ids[TOPK];
        #pragma unroll
        for (int k = 0; k < TOPK; ++k) {
            float mv = vm;
            int   mi = lane;
            #pragma unroll
            for (int off = 32; off > 0; off >>= 1) {
                float ov = __shfl_xor(mv, off);
                int   oi = __shfl_xor(mi, off);
                if (ov > mv || (ov == mv && oi < mi)) { mv = ov; mi = oi; }
            }
            vals[k] = mv; ids[k] = mi;
            if (lane == mi) { vm = -INFINITY; atomicAdd(&hist[mi], 1); }
        }
        if (lane == 0) {
            const float m = vals[0];
            float e[TOPK];
            float ssum = 0.f;
            #pragma unroll
            for (int k = 0; k < TOPK; ++k) { e[k] = expf(vals[k] - m); ssum += e[k]; }
            const float inv = 1.0f / ssum;
            const size_t base = (size_t)(row0 + row) * TOPK;
            #pragma unroll
            for (int k = 0; k < TOPK; ++k) {
                out_scores[base + k] = e[k] * inv;
                out_idx[base + k]    = (float)ids[k];
            }
        }
    }

    __syncthreads();
    if (tid < NEXP) histws[bid * NEXP + tid] = hist[tid];
}

__global__ __launch_bounds__(512) void reduce_kernel(const int* __restrict__ histws,
                                                     float* __restrict__ counts) {
    __shared__ int part[8][NEXP];
    const int t = threadIdx.x;
    const int e = t & 63, c = t >> 6;
    int sm = 0;
    for (int b = c; b < NBLK; b += 8) sm += histws[b * NEXP + e];
    part[c][e] = sm;
    __syncthreads();
    if (t < NEXP) {
        int tot = 0;
        #pragma unroll
        for (int i = 0; i < 8; ++i) tot += part[i][t];
        counts[t] = (float)tot;
    }
}

extern "C" void kernel_launch(void* const* d_in, const int* in_sizes, int n_in,
                              void* d_out, int out_size, void* d_ws, size_t ws_size,
                              hipStream_t stream) {
    const float* x    = (const float*)d_in[0];
    const float* w    = (const float*)d_in[1];
    const float* bias = (const float*)d_in[2];
    float* out = (float*)d_out;
    const int M = in_sizes[0] / DIM;   // 16384 rows

    unsigned int* wpack = (unsigned int*)d_ws;                      // 512 KB
    int* histws = (int*)((char*)d_ws + (size_t)NEXP * DIM * 4);     // 128 KB
    float* out_counts = out + (size_t)2 * M * TOPK;

    prep_kernel<<<64, 256, 0, stream>>>(w, wpack);
    router_kernel<<<NBLK, NT, 0, stream>>>(x, wpack, bias, out, histws, M);
    reduce_kernel<<<1, 512, 0, stream>>>(histws, out_counts);
}